// Round 2
// baseline (1172.271 us; speedup 1.0000x reference)
//
#include <hip/hip_runtime.h>
#include <hip/hip_bf16.h>

#define NNODES 131072
#define NEDGES 2097152
#define BSUB   1024
#define SSUB   128
#define FIN    300
#define FOUT   64

typedef __attribute__((ext_vector_type(8))) short short8;
typedef __attribute__((ext_vector_type(8))) unsigned short ushort8;
typedef __attribute__((ext_vector_type(4))) float f32x4;

__device__ inline short f2bf(float f) {
    unsigned u = __float_as_uint(f);
    u = (u + 0x7FFFu + ((u >> 16) & 1u)) >> 16;   // round-to-nearest-even
    return (short)u;
}

// ---------------------------------------------------------------------------
// Pack W [300][64] f32 into MFMA B-fragment layout, zero-padded to K=320.
// wfrag[((ct*10 + kt)*64 + lane)*8 + e] = bf16(W[kt*32 + (lane>>4)*8 + e][ct*16 + (lane&15)])
// ---------------------------------------------------------------------------
__global__ __launch_bounds__(256) void prep_w_kernel(const float* __restrict__ W,
                                                     short* __restrict__ wfrag) {
    int idx = blockIdx.x * 256 + threadIdx.x;     // 0..2559
    if (idx >= 2560) return;
    int ct   = idx / 640;
    int rem  = idx % 640;
    int kt   = rem / 64;
    int lane = rem % 64;
    int col  = ct * 16 + (lane & 15);
    int kb   = kt * 32 + (lane >> 4) * 8;
#pragma unroll
    for (int e = 0; e < 8; ++e) {
        int k = kb + e;
        float v = (k < FIN) ? W[(size_t)k * FOUT + col] : 0.f;
        wfrag[(size_t)idx * 8 + e] = f2bf(v);
    }
}

// ---------------------------------------------------------------------------
// Per-subgraph edge histogram (gid = src >> 7). LDS hist then merge.
// ---------------------------------------------------------------------------
__global__ __launch_bounds__(256) void count_g_kernel(const int* __restrict__ src,
                                                      int* __restrict__ gcnt) {
    __shared__ int hist[BSUB];
    for (int i = threadIdx.x; i < BSUB; i += 256) hist[i] = 0;
    __syncthreads();
    const int4* sp = (const int4*)(src + (size_t)blockIdx.x * 8192);
    for (int i = threadIdx.x; i < 2048; i += 256) {
        int4 v = sp[i];
        atomicAdd(&hist[v.x >> 7], 1);
        atomicAdd(&hist[v.y >> 7], 1);
        atomicAdd(&hist[v.z >> 7], 1);
        atomicAdd(&hist[v.w >> 7], 1);
    }
    __syncthreads();
    for (int i = threadIdx.x; i < BSUB; i += 256) {
        int c = hist[i];
        if (c) atomicAdd(&gcnt[i], c);
    }
}

// ---------------------------------------------------------------------------
// Exclusive scan of the 1024 bucket counts (single block).
// ---------------------------------------------------------------------------
__global__ __launch_bounds__(256) void scan_g_kernel(const int* __restrict__ gcnt,
                                                     int* __restrict__ goff,
                                                     int* __restrict__ gcur) {
    __shared__ int wsum[4];
    int t = threadIdx.x;            // 0..255, each owns 4 consecutive bins
    int lane = t & 63, w = t >> 6;
    int c0 = gcnt[t * 4], c1 = gcnt[t * 4 + 1], c2 = gcnt[t * 4 + 2], c3 = gcnt[t * 4 + 3];
    int s = c0 + c1 + c2 + c3;
    int pre = s;
#pragma unroll
    for (int o = 1; o < 64; o <<= 1) {
        int v = __shfl_up(pre, o, 64);
        if (lane >= o) pre += v;
    }
    if (lane == 63) wsum[w] = pre;
    __syncthreads();
    int wbase = 0;
    for (int i = 0; i < w; ++i) wbase += wsum[i];
    int excl = wbase + pre - s;
    goff[t * 4] = excl;     gcur[t * 4] = excl;     excl += c0;
    goff[t * 4 + 1] = excl; gcur[t * 4 + 1] = excl; excl += c1;
    goff[t * 4 + 2] = excl; gcur[t * 4 + 2] = excl; excl += c2;
    goff[t * 4 + 3] = excl; gcur[t * 4 + 3] = excl;
}

// ---------------------------------------------------------------------------
// Scatter edges into per-subgraph buckets as packed u16 (src_loc<<7 | dst_loc)
// ---------------------------------------------------------------------------
__global__ __launch_bounds__(256) void scatter_g_kernel(const int* __restrict__ src,
                                                        const int* __restrict__ dst,
                                                        int* __restrict__ gcur,
                                                        unsigned short* __restrict__ bkt) {
    int e = blockIdx.x * 256 + threadIdx.x;
    int s = src[e], d = dst[e];
    int g = s >> 7;
    int p = atomicAdd(&gcur[g], 1);
    bkt[p] = (unsigned short)(((s & 127) << 7) | (d & 127));
}

// ---------------------------------------------------------------------------
// h = in_feat @ W (UNNORMALIZED — deg scaling folded into aggregation),
// bf16 MFMA 16x16x32, output stored as bf16 bits. One wave per 16 rows.
// ---------------------------------------------------------------------------
__global__ __launch_bounds__(256) void gemm_kernel(const float* __restrict__ x,
                                                   const short* __restrict__ wfrag,
                                                   unsigned short* __restrict__ hb) {
    const int wave = threadIdx.x >> 6;
    const int lane = threadIdx.x & 63;
    const int rowbase = (blockIdx.x * 4 + wave) * 16;
    const int arow = rowbase + (lane & 15);
    const int kgrp = lane >> 4;

    f32x4 acc[4];
#pragma unroll
    for (int c = 0; c < 4; ++c) acc[c] = (f32x4){0.f, 0.f, 0.f, 0.f};

    const float* ap = x + (size_t)arow * FIN + kgrp * 8;
#pragma unroll
    for (int kt = 0; kt < 9; ++kt) {
        f32x4 lo = *(const f32x4*)(ap + kt * 32);
        f32x4 hi = *(const f32x4*)(ap + kt * 32 + 4);
        short8 afr;
        afr[0] = f2bf(lo[0]); afr[1] = f2bf(lo[1]);
        afr[2] = f2bf(lo[2]); afr[3] = f2bf(lo[3]);
        afr[4] = f2bf(hi[0]); afr[5] = f2bf(hi[1]);
        afr[6] = f2bf(hi[2]); afr[7] = f2bf(hi[3]);
#pragma unroll
        for (int ct = 0; ct < 4; ++ct) {
            short8 bfr = *(const short8*)(wfrag + ((size_t)(ct * 10 + kt) * 64 + lane) * 8);
            acc[ct] = __builtin_amdgcn_mfma_f32_16x16x32_bf16(afr, bfr, acc[ct], 0, 0, 0);
        }
    }
    {   // K tail: k 288..319, valid only k<300
        short8 afr;
#pragma unroll
        for (int e = 0; e < 8; ++e) {
            int k = 288 + kgrp * 8 + e;
            float v = (k < FIN) ? x[(size_t)arow * FIN + k] : 0.f;
            afr[e] = f2bf(v);
        }
#pragma unroll
        for (int ct = 0; ct < 4; ++ct) {
            short8 bfr = *(const short8*)(wfrag + ((size_t)(ct * 10 + 9) * 64 + lane) * 8);
            acc[ct] = __builtin_amdgcn_mfma_f32_16x16x32_bf16(afr, bfr, acc[ct], 0, 0, 0);
        }
    }
    // D layout: row = (lane>>4)*4 + r, col = ct*16 + (lane&15)
    const int orow = rowbase + (lane >> 4) * 4;
    const int colb = lane & 15;
#pragma unroll
    for (int ct = 0; ct < 4; ++ct)
#pragma unroll
        for (int r = 0; r < 4; ++r)
            hb[(size_t)(orow + r) * FOUT + ct * 16 + colb] = (unsigned short)f2bf(acc[ct][r]);
}

// ---------------------------------------------------------------------------
// Fused per-subgraph: LDS h-tile, in-block degrees, rsqrt(deg_out) pre-scale,
// LDS-atomic aggregation, rsqrt(deg_in)+bias+PReLU, pool+anchor -> out.
// ---------------------------------------------------------------------------
__global__ __launch_bounds__(256) void agg_pool_kernel(const unsigned short* __restrict__ hb,
                                                       const unsigned short* __restrict__ bkt,
                                                       const int* __restrict__ goff,
                                                       const int* __restrict__ gcnt,
                                                       const float* __restrict__ bias,
                                                       const float* __restrict__ prelu,
                                                       float* __restrict__ out) {
    __shared__ float hl[SSUB][FOUT];   // 32 KB
    __shared__ float ac[SSUB][FOUT];   // 32 KB
    __shared__ int   dg[SSUB][2];      // [deg_out, deg_in]
    __shared__ float ps[4][FOUT];

    const int g = blockIdx.x;
    const int t = threadIdx.x;
    const int lane = t & 63;
    const int w = t >> 6;

    // load h tile (bf16 -> f32) + zero acc + zero degrees
    const ushort8* hsrc = (const ushort8*)(hb + (size_t)g * SSUB * FOUT);
    float* hlf = &hl[0][0];
    f32x4* acv = (f32x4*)&ac[0][0];
#pragma unroll
    for (int i = t; i < 1024; i += 256) {
        ushort8 v = hsrc[i];
#pragma unroll
        for (int j = 0; j < 8; ++j)
            hlf[i * 8 + j] = __uint_as_float(((unsigned)v[j]) << 16);
    }
    for (int i = t; i < 2048; i += 256) acv[i] = (f32x4){0.f, 0.f, 0.f, 0.f};
    if (t < SSUB) { dg[t][0] = 0; dg[t][1] = 0; }
    __syncthreads();

    const int off = goff[g];
    const int cnt = gcnt[g];

    // in-block degree count (coalesced u16 reads, LDS int atomics)
    for (int i = t; i < cnt; i += 256) {
        unsigned e = bkt[off + i];
        atomicAdd(&dg[e >> 7][0], 1);
        atomicAdd(&dg[e & 127][1], 1);
    }
    __syncthreads();

    // pre-scale rows by rsqrt(deg_out)
    f32x4* hlv = (f32x4*)hlf;
    for (int i = t; i < 2048; i += 256) {
        int r = i >> 4;                       // 16 f32x4 per row
        float rs = rsqrtf((float)max(dg[r][0], 1));
        f32x4 v = hlv[i];
        v[0] *= rs; v[1] *= rs; v[2] *= rs; v[3] *= rs;
        hlv[i] = v;
    }
    __syncthreads();

    // aggregation: wave per edge, lane = feature; contiguous chunk per wave
    {
        int qc = (cnt + 3) >> 2;
        int start = w * qc;
        int end = min(start + qc, cnt);
        int i = start;
        for (; i + 4 <= end; i += 4) {
            unsigned e0 = bkt[off + i], e1 = bkt[off + i + 1];
            unsigned e2 = bkt[off + i + 2], e3 = bkt[off + i + 3];
            float v0 = hl[e0 >> 7][lane], v1 = hl[e1 >> 7][lane];
            float v2 = hl[e2 >> 7][lane], v3 = hl[e3 >> 7][lane];
            atomicAdd(&ac[e0 & 127][lane], v0);
            atomicAdd(&ac[e1 & 127][lane], v1);
            atomicAdd(&ac[e2 & 127][lane], v2);
            atomicAdd(&ac[e3 & 127][lane], v3);
        }
        for (; i < end; ++i) {
            unsigned e = bkt[off + i];
            atomicAdd(&ac[e & 127][lane], hl[e >> 7][lane]);
        }
    }
    __syncthreads();

    // finalize: *rsqrt(deg_in) + bias, PReLU; pool rows 0..126; anchor row 127
    const float b = bias[lane];
    const float a = prelu[0];
    float pool = 0.f;
    for (int r = w; r < SSUB - 1; r += 4) {
        float v = ac[r][lane] * rsqrtf((float)max(dg[r][1], 1)) + b;
        v = (v > 0.f) ? v : a * v;
        pool += v;
    }
    ps[w][lane] = pool;
    __syncthreads();
    if (w == 0) {
        float s = (ps[0][lane] + ps[1][lane]) + (ps[2][lane] + ps[3][lane]);
        out[(size_t)g * FOUT + lane] = s * (1.0f / 127.0f);
        float v = ac[SSUB - 1][lane] * rsqrtf((float)max(dg[SSUB - 1][1], 1)) + b;
        v = (v > 0.f) ? v : a * v;
        out[(size_t)(BSUB + g) * FOUT + lane] = v;
    }
}

// ---------------------------------------------------------------------------
extern "C" void kernel_launch(void* const* d_in, const int* in_sizes, int n_in,
                              void* d_out, int out_size, void* d_ws, size_t ws_size,
                              hipStream_t stream) {
    const float* in_feat = (const float*)d_in[0];
    const float* W       = (const float*)d_in[1];
    const float* bias    = (const float*)d_in[2];
    const float* prelu   = (const float*)d_in[3];
    const int*   src     = (const int*)d_in[4];
    const int*   dst     = (const int*)d_in[5];
    float* out = (float*)d_out;

    char* ws = (char*)d_ws;
    int*            gcnt  = (int*)(ws);                    // 4 KB
    int*            goff  = (int*)(ws + 4096);             // 4 KB
    int*            gcur  = (int*)(ws + 8192);             // 4 KB
    short*          wfrag = (short*)(ws + 16384);          // 40960 B
    unsigned short* bkt   = (unsigned short*)(ws + 65536); // 4 MB
    unsigned short* hb    = (unsigned short*)(ws + (8u << 20)); // 16 MB bf16 h

    hipMemsetAsync(gcnt, 0, 4096, stream);

    hipLaunchKernelGGL(prep_w_kernel,    dim3(10),           dim3(256), 0, stream, W, wfrag);
    hipLaunchKernelGGL(count_g_kernel,   dim3(NEDGES/8192),  dim3(256), 0, stream, src, gcnt);
    hipLaunchKernelGGL(scan_g_kernel,    dim3(1),            dim3(256), 0, stream, gcnt, goff, gcur);
    hipLaunchKernelGGL(scatter_g_kernel, dim3(NEDGES/256),   dim3(256), 0, stream, src, dst, gcur, bkt);
    hipLaunchKernelGGL(gemm_kernel,      dim3(NNODES/64),    dim3(256), 0, stream, in_feat, wfrag, hb);
    hipLaunchKernelGGL(agg_pool_kernel,  dim3(BSUB),         dim3(256), 0, stream, hb, bkt, goff, gcnt, bias, prelu, out);
}

// Round 3
// 125.666 us; speedup vs baseline: 9.3284x; 9.3284x over previous
//
#include <hip/hip_runtime.h>
#include <hip/hip_bf16.h>

#define NNODES 131072
#define NEDGES 2097152
#define BSUB   1024
#define SSUB   128
#define FIN    300
#define FOUT   64
#define NCHUNK 256
#define CHEDGE 8192

typedef __attribute__((ext_vector_type(8))) short short8;
typedef __attribute__((ext_vector_type(8))) unsigned short ushort8;
typedef __attribute__((ext_vector_type(4))) float f32x4;

__device__ inline short f2bf(float f) {
    unsigned u = __float_as_uint(f);
    u = (u + 0x7FFFu + ((u >> 16) & 1u)) >> 16;   // round-to-nearest-even
    return (short)u;
}
__device__ inline float bf2f(unsigned short b) {
    return __uint_as_float(((unsigned)b) << 16);
}

// ---------------------------------------------------------------------------
// Pack W [300][64] f32 into MFMA B-fragment layout, zero-padded to K=320.
// ---------------------------------------------------------------------------
__global__ __launch_bounds__(256) void prep_w_kernel(const float* __restrict__ W,
                                                     short* __restrict__ wfrag) {
    int idx = blockIdx.x * 256 + threadIdx.x;     // 0..2559
    if (idx >= 2560) return;
    int ct   = idx / 640;
    int rem  = idx % 640;
    int kt   = rem / 64;
    int lane = rem % 64;
    int col  = ct * 16 + (lane & 15);
    int kb   = kt * 32 + (lane >> 4) * 8;
#pragma unroll
    for (int e = 0; e < 8; ++e) {
        int k = kb + e;
        float v = (k < FIN) ? W[(size_t)k * FOUT + col] : 0.f;
        wfrag[(size_t)idx * 8 + e] = f2bf(v);
    }
}

// ---------------------------------------------------------------------------
// Per-chunk histogram over 1024 subgraphs; ONE global atomic per nonzero bin
// reserves this chunk's slot range inside bucket g. cbase[chunk][g] = base.
// ---------------------------------------------------------------------------
__global__ __launch_bounds__(256) void count_chunk_kernel(const int* __restrict__ src,
                                                          int* __restrict__ gcnt,
                                                          int* __restrict__ cbase) {
    __shared__ int hist[BSUB];
    const int t = threadIdx.x;
    for (int i = t; i < BSUB; i += 256) hist[i] = 0;
    __syncthreads();
    const int4* sp = (const int4*)(src + (size_t)blockIdx.x * CHEDGE);
    for (int i = t; i < CHEDGE / 4; i += 256) {
        int4 v = sp[i];
        atomicAdd(&hist[v.x >> 7], 1);
        atomicAdd(&hist[v.y >> 7], 1);
        atomicAdd(&hist[v.z >> 7], 1);
        atomicAdd(&hist[v.w >> 7], 1);
    }
    __syncthreads();
    for (int g = t; g < BSUB; g += 256) {
        int c = hist[g];
        if (c) cbase[blockIdx.x * BSUB + g] = atomicAdd(&gcnt[g], c);
    }
}

// ---------------------------------------------------------------------------
// Scatter packed edges (src_loc<<7 | dst_loc) into fixed 4096-entry buckets.
// Ranks via LDS int atomics starting from the chunk's reserved base.
// ---------------------------------------------------------------------------
__global__ __launch_bounds__(256) void scatter_chunk_kernel(const int* __restrict__ src,
                                                            const int* __restrict__ dst,
                                                            const int* __restrict__ cbase,
                                                            unsigned short* __restrict__ bkt) {
    __shared__ int cur[BSUB];
    const int t = threadIdx.x;
    for (int g = t; g < BSUB; g += 256) cur[g] = cbase[blockIdx.x * BSUB + g];
    __syncthreads();
    const int4* sp = (const int4*)(src + (size_t)blockIdx.x * CHEDGE);
    const int4* dp = (const int4*)(dst + (size_t)blockIdx.x * CHEDGE);
    for (int i = t; i < CHEDGE / 4; i += 256) {
        int4 s4 = sp[i];
        int4 d4 = dp[i];
#pragma unroll
        for (int k = 0; k < 4; ++k) {
            int s = (k == 0) ? s4.x : (k == 1) ? s4.y : (k == 2) ? s4.z : s4.w;
            int d = (k == 0) ? d4.x : (k == 1) ? d4.y : (k == 2) ? d4.z : d4.w;
            int g = s >> 7;
            int r = atomicAdd(&cur[g], 1);
            bkt[((size_t)g << 12) + r] = (unsigned short)(((s & 127) << 7) | (d & 127));
        }
    }
}

// ---------------------------------------------------------------------------
// h = in_feat @ W (unnormalized), bf16 MFMA 16x16x32, bf16 output.
// ---------------------------------------------------------------------------
__global__ __launch_bounds__(256) void gemm_kernel(const float* __restrict__ x,
                                                   const short* __restrict__ wfrag,
                                                   unsigned short* __restrict__ hb) {
    const int wave = threadIdx.x >> 6;
    const int lane = threadIdx.x & 63;
    const int rowbase = (blockIdx.x * 4 + wave) * 16;
    const int arow = rowbase + (lane & 15);
    const int kgrp = lane >> 4;

    f32x4 acc[4];
#pragma unroll
    for (int c = 0; c < 4; ++c) acc[c] = (f32x4){0.f, 0.f, 0.f, 0.f};

    const float* ap = x + (size_t)arow * FIN + kgrp * 8;
#pragma unroll
    for (int kt = 0; kt < 9; ++kt) {
        f32x4 lo = *(const f32x4*)(ap + kt * 32);
        f32x4 hi = *(const f32x4*)(ap + kt * 32 + 4);
        short8 afr;
        afr[0] = f2bf(lo[0]); afr[1] = f2bf(lo[1]);
        afr[2] = f2bf(lo[2]); afr[3] = f2bf(lo[3]);
        afr[4] = f2bf(hi[0]); afr[5] = f2bf(hi[1]);
        afr[6] = f2bf(hi[2]); afr[7] = f2bf(hi[3]);
#pragma unroll
        for (int ct = 0; ct < 4; ++ct) {
            short8 bfr = *(const short8*)(wfrag + ((size_t)(ct * 10 + kt) * 64 + lane) * 8);
            acc[ct] = __builtin_amdgcn_mfma_f32_16x16x32_bf16(afr, bfr, acc[ct], 0, 0, 0);
        }
    }
    {   // K tail: k 288..319, valid only k<300
        short8 afr;
#pragma unroll
        for (int e = 0; e < 8; ++e) {
            int k = 288 + kgrp * 8 + e;
            float v = (k < FIN) ? x[(size_t)arow * FIN + k] : 0.f;
            afr[e] = f2bf(v);
        }
#pragma unroll
        for (int ct = 0; ct < 4; ++ct) {
            short8 bfr = *(const short8*)(wfrag + ((size_t)(ct * 10 + 9) * 64 + lane) * 8);
            acc[ct] = __builtin_amdgcn_mfma_f32_16x16x32_bf16(afr, bfr, acc[ct], 0, 0, 0);
        }
    }
    const int orow = rowbase + (lane >> 4) * 4;
    const int colb = lane & 15;
#pragma unroll
    for (int ct = 0; ct < 4; ++ct)
#pragma unroll
        for (int r = 0; r < 4; ++r)
            hb[(size_t)(orow + r) * FOUT + ct * 16 + colb] = (unsigned short)f2bf(acc[ct][r]);
}

// ---------------------------------------------------------------------------
// Fused per-subgraph aggregate + norm + PReLU + pool + anchor.
// NO float atomics: edges bucketed by dst into LDS (int atomics for ranks),
// then register accumulation, wave-owned dst rows.
// ---------------------------------------------------------------------------
__global__ __launch_bounds__(256) void agg_pool_kernel(const unsigned short* __restrict__ hb,
                                                       const unsigned short* __restrict__ bkt,
                                                       const int* __restrict__ gcnt,
                                                       const float* __restrict__ bias,
                                                       const float* __restrict__ prelu,
                                                       float* __restrict__ out) {
    __shared__ unsigned short hl[SSUB][FOUT];       // 16 KB bf16 bits
    __shared__ unsigned char  es[SSUB][64];         // 8 KB per-dst src lists
    __shared__ int din[SSUB];
    __shared__ int dout[SSUB];
    __shared__ float ps[4][FOUT];

    const int g = blockIdx.x;
    const int t = threadIdx.x;
    const int lane = t & 63;
    const int w = t >> 6;

    // load h tile (straight bf16 copy, 4 x ushort8 per thread)
    {
        const ushort8* hsrc = (const ushort8*)(hb + (size_t)g * SSUB * FOUT);
        ushort8* hdst = (ushort8*)&hl[0][0];
        for (int i = t; i < 1024; i += 256) hdst[i] = hsrc[i];
    }
    if (t < SSUB) { din[t] = 0; dout[t] = 0; }
    __syncthreads();

    const int cnt = gcnt[g];
    const unsigned short* eb = bkt + ((size_t)g << 12);

    // bucket edges by dst into LDS (int atomics only)
    for (int i = t; i < cnt; i += 256) {
        unsigned e = eb[i];
        int s = e >> 7, d = e & 127;
        int r = atomicAdd(&din[d], 1);
        es[d][r & 63] = (unsigned char)s;
        atomicAdd(&dout[s], 1);
    }
    __syncthreads();

    // pre-scale hl rows by rsqrt(deg_out) (bf16 in place)
    {
        ushort8* hlv = (ushort8*)&hl[0][0];
        for (int i = t; i < 1024; i += 256) {          // 4 iters; 8 elems same row
            int r = i >> 3;
            float rs = rsqrtf((float)max(dout[r], 1));
            ushort8 v = hlv[i];
#pragma unroll
            for (int j = 0; j < 8; ++j)
                v[j] = (unsigned short)f2bf(bf2f(v[j]) * rs);
            hlv[i] = v;
        }
    }
    __syncthreads();

    // register aggregation: wave w owns dst rows w, w+4, ...
    const float bv = bias[lane];
    const float a = prelu[0];
    float pool = 0.f;
#pragma unroll 4
    for (int ii = 0; ii < 32; ++ii) {
        int d = w + 4 * ii;
        int cd = min(din[d], 64);
        float acc = 0.f;
        const unsigned* ew = (const unsigned*)&es[d][0];
        int nw = (cd + 3) >> 2;
        for (int p = 0; p < nw; ++p) {
            unsigned wd = ew[p];                        // broadcast LDS read
            int rem = cd - p * 4;
#pragma unroll
            for (int b = 0; b < 4; ++b) {
                if (b < rem) {                          // wave-uniform predicate
                    int s = (wd >> (8 * b)) & 127;
                    acc += bf2f(hl[s][lane]);
                }
            }
        }
        float v = acc * rsqrtf((float)max(din[d], 1)) + bv;
        v = (v > 0.f) ? v : a * v;
        if (d == SSUB - 1)
            out[(size_t)(BSUB + g) * FOUT + lane] = v;  // anchor (wave 3)
        else
            pool += v;
    }
    ps[w][lane] = pool;
    __syncthreads();
    if (w == 0) {
        float s = (ps[0][lane] + ps[1][lane]) + (ps[2][lane] + ps[3][lane]);
        out[(size_t)g * FOUT + lane] = s * (1.0f / 127.0f);
    }
}

// ---------------------------------------------------------------------------
extern "C" void kernel_launch(void* const* d_in, const int* in_sizes, int n_in,
                              void* d_out, int out_size, void* d_ws, size_t ws_size,
                              hipStream_t stream) {
    const float* in_feat = (const float*)d_in[0];
    const float* W       = (const float*)d_in[1];
    const float* bias    = (const float*)d_in[2];
    const float* prelu   = (const float*)d_in[3];
    const int*   src     = (const int*)d_in[4];
    const int*   dst     = (const int*)d_in[5];
    float* out = (float*)d_out;

    char* ws = (char*)d_ws;
    int*            gcnt  = (int*)(ws);                        // 4 KB
    int*            cbase = (int*)(ws + 65536);                // 1 MB (256x1024)
    short*          wfrag = (short*)(ws + 65536 + 1048576);    // 40 KB
    unsigned short* bkt   = (unsigned short*)(ws + (2u << 20)); // 8 MB (1024x4096 u16)
    unsigned short* hb    = (unsigned short*)(ws + (16u << 20)); // 16 MB bf16 h

    hipMemsetAsync(gcnt, 0, 4096, stream);

    hipLaunchKernelGGL(prep_w_kernel,       dim3(10),     dim3(256), 0, stream, W, wfrag);
    hipLaunchKernelGGL(count_chunk_kernel,  dim3(NCHUNK), dim3(256), 0, stream, src, gcnt, cbase);
    hipLaunchKernelGGL(scatter_chunk_kernel,dim3(NCHUNK), dim3(256), 0, stream, src, dst, cbase, bkt);
    hipLaunchKernelGGL(gemm_kernel,         dim3(NNODES/64), dim3(256), 0, stream, in_feat, wfrag, hb);
    hipLaunchKernelGGL(agg_pool_kernel,     dim3(BSUB),   dim3(256), 0, stream, hb, bkt, gcnt, bias, prelu, out);
}

// Round 4
// 112.719 us; speedup vs baseline: 10.3999x; 1.1149x over previous
//
#include <hip/hip_runtime.h>
#include <hip/hip_bf16.h>

#define NNODES 131072
#define NEDGES 2097152
#define BSUB   1024
#define SSUB   128
#define FIN    300
#define FOUT   64
#define NCHUNK 256
#define CHEDGE 8192

typedef __attribute__((ext_vector_type(8))) short short8;
typedef __attribute__((ext_vector_type(8))) unsigned short ushort8;
typedef __attribute__((ext_vector_type(4))) float f32x4;

__device__ inline short f2bf(float f) {
    unsigned u = __float_as_uint(f);
    u = (u + 0x7FFFu + ((u >> 16) & 1u)) >> 16;   // round-to-nearest-even
    return (short)u;
}
__device__ inline float bf2f(unsigned short b) {
    return __uint_as_float(((unsigned)b) << 16);
}

// ---------------------------------------------------------------------------
// Pack W [300][64] f32 into MFMA B-fragment layout (K padded to 320) AND
// zero the 1024-entry gcnt array (replaces the pathological graph-memset node,
// which cost ~91 us per replay). Stream order makes this safe.
// ---------------------------------------------------------------------------
__global__ __launch_bounds__(256) void prep_w_kernel(const float* __restrict__ W,
                                                     short* __restrict__ wfrag,
                                                     int* __restrict__ gcnt) {
    int idx = blockIdx.x * 256 + threadIdx.x;     // grid 10 x 256 = 2560
    if (idx < BSUB) gcnt[idx] = 0;
    if (idx >= 2560) return;
    int ct   = idx / 640;
    int rem  = idx % 640;
    int kt   = rem / 64;
    int lane = rem % 64;
    int col  = ct * 16 + (lane & 15);
    int kb   = kt * 32 + (lane >> 4) * 8;
#pragma unroll
    for (int e = 0; e < 8; ++e) {
        int k = kb + e;
        float v = (k < FIN) ? W[(size_t)k * FOUT + col] : 0.f;
        wfrag[(size_t)idx * 8 + e] = f2bf(v);
    }
}

// ---------------------------------------------------------------------------
// Single-pass edge bucketing: stage chunk edges in LDS, histogram, reserve a
// range per (chunk, subgraph) with ONE global atomic per nonzero bin, scatter
// packed (src_loc<<7 | dst_loc) u16 edges into fixed 4096-entry buckets.
// ---------------------------------------------------------------------------
__global__ __launch_bounds__(256) void bucket_kernel(const int* __restrict__ src,
                                                     const int* __restrict__ dst,
                                                     int* __restrict__ gcnt,
                                                     unsigned short* __restrict__ bkt) {
    __shared__ unsigned short epack[CHEDGE];   // 16 KB
    __shared__ unsigned short eg[CHEDGE];      // 16 KB
    __shared__ int hist[BSUB];                 // 4 KB (hist, then cursor)
    const int t = threadIdx.x;
    for (int i = t; i < BSUB; i += 256) hist[i] = 0;
    __syncthreads();
    const int4* sp = (const int4*)(src + (size_t)blockIdx.x * CHEDGE);
    const int4* dp = (const int4*)(dst + (size_t)blockIdx.x * CHEDGE);
    for (int i = t; i < CHEDGE / 4; i += 256) {
        int4 s4 = sp[i], d4 = dp[i];
#pragma unroll
        for (int k = 0; k < 4; ++k) {
            int s = (k == 0) ? s4.x : (k == 1) ? s4.y : (k == 2) ? s4.z : s4.w;
            int d = (k == 0) ? d4.x : (k == 1) ? d4.y : (k == 2) ? d4.z : d4.w;
            int g = s >> 7;
            epack[i * 4 + k] = (unsigned short)(((s & 127) << 7) | (d & 127));
            eg[i * 4 + k] = (unsigned short)g;
            atomicAdd(&hist[g], 1);
        }
    }
    __syncthreads();
    for (int i = t; i < BSUB; i += 256) {
        int c = hist[i];
        hist[i] = c ? atomicAdd(&gcnt[i], c) : 0;   // hist becomes running cursor
    }
    __syncthreads();
    for (int i = t; i < CHEDGE; i += 256) {
        int g = eg[i];
        int r = atomicAdd(&hist[g], 1);
        bkt[((size_t)g << 12) + r] = epack[i];
    }
}

// ---------------------------------------------------------------------------
// Fully fused per-subgraph: MFMA GEMM (128x300 @ 300x64) -> LDS bf16 tile,
// in-block degrees from bucketed edges, register aggregation with f32
// rsqrt(deg_out) scaling, rsqrt(deg_in)+bias+PReLU, pool + anchor -> out.
// One block per subgraph, 4 waves; wave w owns rows w*32..w*32+31 for GEMM
// and dst rows w, w+4, ... for aggregation.
// ---------------------------------------------------------------------------
__global__ __launch_bounds__(256) void gcn_fused_kernel(const float* __restrict__ x,
                                                        const short* __restrict__ wfrag,
                                                        const unsigned short* __restrict__ bkt,
                                                        const int* __restrict__ gcnt,
                                                        const float* __restrict__ bias,
                                                        const float* __restrict__ prelu,
                                                        float* __restrict__ out) {
    __shared__ unsigned short hl[SSUB][FOUT];   // 16 KB bf16 h-tile
    __shared__ unsigned char  es[SSUB][64];     // 8 KB per-dst src lists
    __shared__ int   din[SSUB];                 // 512 B
    __shared__ int   dout[SSUB];                // 512 B
    __shared__ float rout[SSUB];                // 512 B
    __shared__ float ps[4][FOUT];               // 1 KB

    const int g = blockIdx.x;
    const int t = threadIdx.x;
    const int lane = t & 63;
    const int w = t >> 6;

    if (t < SSUB) { din[t] = 0; dout[t] = 0; }
    __syncthreads();

    // ---- edge pass: bucket by dst into LDS, count degrees (int atomics) ----
    const int cnt = gcnt[g];
    const unsigned short* eb = bkt + ((size_t)g << 12);
    for (int i = t; i < cnt; i += 256) {
        unsigned e = eb[i];
        int s = e >> 7, d = e & 127;
        int r = atomicAdd(&din[d], 1);
        es[d][r & 63] = (unsigned char)s;
        atomicAdd(&dout[s], 1);
    }

    // ---- GEMM: rows g*128 + w*32 + {0..31}, two 16-row tiles ----
    f32x4 acc[2][4];
#pragma unroll
    for (int rt = 0; rt < 2; ++rt)
#pragma unroll
        for (int c = 0; c < 4; ++c) acc[rt][c] = (f32x4){0.f, 0.f, 0.f, 0.f};

    const int kgrp = lane >> 4;
#pragma unroll
    for (int rt = 0; rt < 2; ++rt) {
        const int arow = g * SSUB + w * 32 + rt * 16 + (lane & 15);
        const float* ap = x + (size_t)arow * FIN + kgrp * 8;
#pragma unroll
        for (int kt = 0; kt < 9; ++kt) {
            f32x4 lo = *(const f32x4*)(ap + kt * 32);
            f32x4 hi = *(const f32x4*)(ap + kt * 32 + 4);
            short8 afr;
            afr[0] = f2bf(lo[0]); afr[1] = f2bf(lo[1]);
            afr[2] = f2bf(lo[2]); afr[3] = f2bf(lo[3]);
            afr[4] = f2bf(hi[0]); afr[5] = f2bf(hi[1]);
            afr[6] = f2bf(hi[2]); afr[7] = f2bf(hi[3]);
#pragma unroll
            for (int ct = 0; ct < 4; ++ct) {
                short8 bfr = *(const short8*)(wfrag + ((size_t)(ct * 10 + kt) * 64 + lane) * 8);
                acc[rt][ct] = __builtin_amdgcn_mfma_f32_16x16x32_bf16(afr, bfr, acc[rt][ct], 0, 0, 0);
            }
        }
        {   // K tail: k 288..319, valid only k<300
            short8 afr;
#pragma unroll
            for (int e = 0; e < 8; ++e) {
                int k = 288 + kgrp * 8 + e;
                float v = (k < FIN) ? x[(size_t)arow * FIN + k] : 0.f;
                afr[e] = f2bf(v);
            }
#pragma unroll
            for (int ct = 0; ct < 4; ++ct) {
                short8 bfr = *(const short8*)(wfrag + ((size_t)(ct * 10 + 9) * 64 + lane) * 8);
                acc[rt][ct] = __builtin_amdgcn_mfma_f32_16x16x32_bf16(afr, bfr, acc[rt][ct], 0, 0, 0);
            }
        }
    }
    __syncthreads();   // edge atomics complete; safe to write hl & read dout

    // ---- write h tile to LDS (bf16), D layout row=(lane>>4)*4+r, col=ct*16+(lane&15)
#pragma unroll
    for (int rt = 0; rt < 2; ++rt) {
        const int lrow = w * 32 + rt * 16 + (lane >> 4) * 4;
        const int colb = lane & 15;
#pragma unroll
        for (int ct = 0; ct < 4; ++ct)
#pragma unroll
            for (int r = 0; r < 4; ++r)
                hl[lrow + r][ct * 16 + colb] = (unsigned short)f2bf(acc[rt][ct][r]);
    }
    if (t < SSUB) rout[t] = rsqrtf((float)max(dout[t], 1));
    __syncthreads();

    // ---- aggregation: wave w owns dst rows w, w+4, ...; f32 scale by rout[s]
    const float bv = bias[lane];
    const float a = prelu[0];
    float pool = 0.f;
#pragma unroll 4
    for (int ii = 0; ii < 32; ++ii) {
        int d = w + 4 * ii;
        int cd = min(din[d], 64);
        float accv = 0.f;
        const unsigned* ew = (const unsigned*)&es[d][0];
        int nw = (cd + 3) >> 2;
        for (int p = 0; p < nw; ++p) {
            unsigned wd = ew[p];                    // broadcast LDS read
            int rem = cd - p * 4;
#pragma unroll
            for (int b = 0; b < 4; ++b) {
                if (b < rem) {                      // wave-uniform predicate
                    int s = (wd >> (8 * b)) & 127;
                    accv += bf2f(hl[s][lane]) * rout[s];
                }
            }
        }
        float v = accv * rsqrtf((float)max(din[d], 1)) + bv;
        v = (v > 0.f) ? v : a * v;
        if (d == SSUB - 1)
            out[(size_t)(BSUB + g) * FOUT + lane] = v;   // anchor (wave 3)
        else
            pool += v;
    }
    ps[w][lane] = pool;
    __syncthreads();
    if (w == 0) {
        float s = (ps[0][lane] + ps[1][lane]) + (ps[2][lane] + ps[3][lane]);
        out[(size_t)g * FOUT + lane] = s * (1.0f / 127.0f);
    }
}

// ---------------------------------------------------------------------------
extern "C" void kernel_launch(void* const* d_in, const int* in_sizes, int n_in,
                              void* d_out, int out_size, void* d_ws, size_t ws_size,
                              hipStream_t stream) {
    const float* in_feat = (const float*)d_in[0];
    const float* W       = (const float*)d_in[1];
    const float* bias    = (const float*)d_in[2];
    const float* prelu   = (const float*)d_in[3];
    const int*   src     = (const int*)d_in[4];
    const int*   dst     = (const int*)d_in[5];
    float* out = (float*)d_out;

    char* ws = (char*)d_ws;
    int*            gcnt  = (int*)(ws);                         // 4 KB
    short*          wfrag = (short*)(ws + 65536);               // 40 KB
    unsigned short* bkt   = (unsigned short*)(ws + (1u << 20)); // 8 MB (1024 x 4096 u16)

    hipLaunchKernelGGL(prep_w_kernel,   dim3(10),       dim3(256), 0, stream, W, wfrag, gcnt);
    hipLaunchKernelGGL(bucket_kernel,   dim3(NCHUNK),   dim3(256), 0, stream, src, dst, gcnt, bkt);
    hipLaunchKernelGGL(gcn_fused_kernel,dim3(BSUB),     dim3(256), 0, stream, in_feat, wfrag, bkt, gcnt, bias, prelu, out);
}